// Round 3
// baseline (4407.874 us; speedup 1.0000x reference)
//
#include <hip/hip_runtime.h>
#include <hip/hip_bf16.h>

#define RESN 64
#define NS 24
#define WD 256
#define SD 256
#define NB 2
#define RPB 4          // rays per block
#define MP 96          // points per block = RPB*NS
#define NTH 512
#define NBLK 2048      // (NB*RESN*RESN)/RPB

typedef unsigned short u16;
typedef unsigned int u32;

__device__ __forceinline__ float sigm(float x){ return 1.0f / (1.0f + expf(-x)); }

// ---------------- kernel 1: FiLM gamma/beta per (layer, batch, out) ----------------
// G/Bt layout: [(l*NB + b)*WD + o], l in 0..8 (0..7 = film layers, 8 = view layer)
__global__ void film_kernel(const float* styles, const float* gw8, const float* gb8,
                            const float* bw8, const float* bb8,
                            const float* vgw, const float* vgb, const float* vbw, const float* vbb,
                            float* G, float* Bt){
  int l = blockIdx.x >> 1, b = blockIdx.x & 1, o = threadIdx.x;
  __shared__ float st[SD];
  st[o] = styles[b * SD + o];
  __syncthreads();
  const float *gw, *bw; float gbv, bbv;
  if (l < 8){
    gw = gw8 + ((size_t)l * WD + o) * SD; bw = bw8 + ((size_t)l * WD + o) * SD;
    gbv = gb8[l * WD + o];                bbv = bb8[l * WD + o];
  } else {
    gw = vgw + (size_t)o * SD;            bw = vbw + (size_t)o * SD;
    gbv = vgb[o];                         bbv = vbb[o];
  }
  float ag = 0.f, ab = 0.f;
  for (int s = 0; s < SD; s += 2){
    ag += st[s] * gw[s] + st[s+1] * gw[s+1];
    ab += st[s] * bw[s] + st[s+1] * bw[s+1];
  }
  int idx = (l * NB + b) * WD + o;
  G[idx]  = 15.0f * (ag + gbv) + 30.0f;
  Bt[idx] = 0.25f * (ab + bbv);
}

// ---------------- kernel 2: fused renderer ----------------
// 512 threads: om = t&127 -> output pair o0=2*om, o1=o0+1 ; mg = t>>7 -> ray group (24 samples)
__launch_bounds__(NTH, 2)
__global__ void render_kernel(
    const float* pose, const float* focal, const float* nearv, const float* farv,
    const float* w0, const float* b0, const float* wsp, const float* bsp,
    const float* vw, const float* vb,
    const float* rgbw, const float* rgbb, const float* sgw, const float* sgb,
    const float* sbeta, const float* G, const float* Bt, float* out)
{
  __shared__ float hl[MP][WD];          // 96 KB activation tile
  __shared__ float xl[MP][4];
  __shared__ float vd[RPB][4];
  __shared__ float dn[RPB];
  __shared__ float sdfl[MP];
  __shared__ float rgbl[MP][4];
  __shared__ float wtl[RPB][NS];
  __shared__ float swl[WD];
  __shared__ float rwl[3][WD];

  const int t   = threadIdx.x;
  const int om  = t & 127;
  const int mg  = t >> 7;
  const int o0  = om * 2, o1 = om * 2 + 1;
  const int mb  = mg * NS;
  const int blk = blockIdx.x;
  const int ray0 = blk * RPB;
  const int bidx = ray0 >> 12;          // / (RESN*RESN)

  // small-weight preload
  if (t < WD) swl[t] = sgw[t];
  for (int i = t; i < 3 * WD; i += NTH) ((float*)rwl)[i] = rgbw[i];

  // ---- point setup (threads 0..95) ----
  if (t < MP){
    int m  = t;
    int s  = m % NS;
    int rl = m / NS;
    int ray = ray0 + rl;
    int ww = ray & (RESN - 1);
    int hh = (ray >> 6) & (RESN - 1);
    float f  = focal[bidx];
    float nr = nearv[bidx];
    float fr = farv[bidx];
    float di = ((ww + 0.5f) - RESN * 0.5f) / f;
    float dj = -(((hh + 0.5f) - RESN * 0.5f) / f);
    float dk = -1.0f;
    const float* P = pose + bidx * 12;
    float rdx = di * P[0] + dj * P[1] + dk * P[2];
    float rdy = di * P[4] + dj * P[5] + dk * P[6];
    float rdz = di * P[8] + dj * P[9] + dk * P[10];
    float ox = P[3], oy = P[7], oz = P[11];
    float nrm = sqrtf(rdx * rdx + rdy * rdy + rdz * rdz);
    const float C = (1.0f - 1.0f / NS) / (NS - 1);
    float tv = s * C;
    float z  = nr * (1.0f - tv) + fr * tv;
    float sc = 2.0f / (fr - nr);
    xl[m][0] = (ox + rdx * z) * sc;
    xl[m][1] = (oy + rdy * z) * sc;
    xl[m][2] = (oz + rdz * z) * sc;
    if (s == 0){
      vd[rl][0] = rdx / nrm; vd[rl][1] = rdy / nrm; vd[rl][2] = rdz / nrm;
      dn[rl] = nrm;
    }
  }
  __syncthreads();

  // ---- layer 0: 3 -> 256 FiLM ----
  {
    float wa[3], wbv[3];
    #pragma unroll
    for (int j = 0; j < 3; j++){ wa[j] = w0[o0 * 3 + j]; wbv[j] = w0[o1 * 3 + j]; }
    float bi0 = b0[o0], bi1 = b0[o1];
    float g0 = G[bidx * WD + o0],  g1 = G[bidx * WD + o1];
    float e0 = Bt[bidx * WD + o0], e1 = Bt[bidx * WD + o1];
    #pragma unroll
    for (int m = 0; m < NS; m++){
      float x0 = xl[mb + m][0], x1 = xl[mb + m][1], x2 = xl[mb + m][2];
      float u0 = x0 * wa[0]  + x1 * wa[1]  + x2 * wa[2]  + bi0;
      float u1 = x0 * wbv[0] + x1 * wbv[1] + x2 * wbv[2] + bi1;
      float2 hv; hv.x = sinf(g0 * u0 + e0); hv.y = sinf(g1 * u1 + e1);
      *(float2*)&hl[mb + m][o0] = hv;
    }
  }
  __syncthreads();

  // ---- 7 hidden layers: 256 -> 256 FiLM ----
  #pragma unroll 1
  for (int l = 0; l < 7; l++){
    const float* wl = wsp + (size_t)l * WD * WD;
    float a0[NS], a1[NS];
    #pragma unroll
    for (int m = 0; m < NS; m++){ a0[m] = 0.f; a1[m] = 0.f; }
    #pragma unroll 1
    for (int kc = 0; kc < 8; kc++){
      float wr0[32], wr1[32];
      const float4* p0 = (const float4*)(wl + (size_t)o0 * WD + kc * 32);
      const float4* p1 = (const float4*)(wl + (size_t)o1 * WD + kc * 32);
      #pragma unroll
      for (int q = 0; q < 8; q++){
        float4 u0 = p0[q], u1 = p1[q];
        wr0[q*4+0] = u0.x; wr0[q*4+1] = u0.y; wr0[q*4+2] = u0.z; wr0[q*4+3] = u0.w;
        wr1[q*4+0] = u1.x; wr1[q*4+1] = u1.y; wr1[q*4+2] = u1.z; wr1[q*4+3] = u1.w;
      }
      #pragma unroll
      for (int m = 0; m < NS; m++){
        const float4* hp = (const float4*)&hl[mb + m][kc * 32];
        #pragma unroll
        for (int q = 0; q < 8; q++){
          float4 h4 = hp[q];
          a0[m] = fmaf(h4.x, wr0[q*4+0], a0[m]);
          a0[m] = fmaf(h4.y, wr0[q*4+1], a0[m]);
          a0[m] = fmaf(h4.z, wr0[q*4+2], a0[m]);
          a0[m] = fmaf(h4.w, wr0[q*4+3], a0[m]);
          a1[m] = fmaf(h4.x, wr1[q*4+0], a1[m]);
          a1[m] = fmaf(h4.y, wr1[q*4+1], a1[m]);
          a1[m] = fmaf(h4.z, wr1[q*4+2], a1[m]);
          a1[m] = fmaf(h4.w, wr1[q*4+3], a1[m]);
        }
      }
    }
    int gi = (l + 1) * NB + bidx;
    float g0 = G[gi * WD + o0],  g1 = G[gi * WD + o1];
    float e0 = Bt[gi * WD + o0], e1 = Bt[gi * WD + o1];
    float bi0 = bsp[l * WD + o0], bi1 = bsp[l * WD + o1];
    __syncthreads();   // everyone done reading hl
    #pragma unroll
    for (int m = 0; m < NS; m++){
      float2 hv;
      hv.x = sinf(g0 * (a0[m] + bi0) + e0);
      hv.y = sinf(g1 * (a1[m] + bi1) + e1);
      *(float2*)&hl[mb + m][o0] = hv;
    }
    __syncthreads();
  }

  // ---- sigma head (reads final hidden h) ----
  if (t < MP){
    float a = 0.f;
    #pragma unroll 4
    for (int q = 0; q < 64; q++){
      int qq = (q + t) & 63;                       // rotate to spread banks
      float4 h4 = *(const float4*)&hl[t][qq * 4];
      float4 w4 = *(const float4*)&swl[qq * 4];
      a += h4.x * w4.x + h4.y * w4.y + h4.z * w4.z + h4.w * w4.w;
    }
    sdfl[t] = a + sgb[0];
  }

  // ---- view layer: (256 h + 3 dir) -> 256 FiLM ----
  {
    float a0[NS], a1[NS];
    #pragma unroll
    for (int m = 0; m < NS; m++){ a0[m] = 0.f; a1[m] = 0.f; }
    #pragma unroll 1
    for (int kc = 0; kc < 8; kc++){
      float wr0[32], wr1[32];
      const float* r0 = vw + (size_t)o0 * 259 + kc * 32;
      const float* r1 = vw + (size_t)o1 * 259 + kc * 32;
      #pragma unroll
      for (int j = 0; j < 32; j += 2){
        float2 v0 = *(const float2*)(r0 + j);   // o0*259 is even -> 8B aligned
        wr0[j] = v0.x; wr0[j+1] = v0.y;
      }
      #pragma unroll
      for (int j = 0; j < 32; j++){ wr1[j] = r1[j]; }  // odd row: scalar
      #pragma unroll
      for (int m = 0; m < NS; m++){
        const float4* hp = (const float4*)&hl[mb + m][kc * 32];
        #pragma unroll
        for (int q = 0; q < 8; q++){
          float4 h4 = hp[q];
          a0[m] = fmaf(h4.x, wr0[q*4+0], a0[m]);
          a0[m] = fmaf(h4.y, wr0[q*4+1], a0[m]);
          a0[m] = fmaf(h4.z, wr0[q*4+2], a0[m]);
          a0[m] = fmaf(h4.w, wr0[q*4+3], a0[m]);
          a1[m] = fmaf(h4.x, wr1[q*4+0], a1[m]);
          a1[m] = fmaf(h4.y, wr1[q*4+1], a1[m]);
          a1[m] = fmaf(h4.z, wr1[q*4+2], a1[m]);
          a1[m] = fmaf(h4.w, wr1[q*4+3], a1[m]);
        }
      }
    }
    // direction terms + bias (constant across the 24 samples of this ray)
    float dv0 = vd[mg][0], dv1 = vd[mg][1], dv2 = vd[mg][2];
    float c0 = dv0 * vw[(size_t)o0 * 259 + 256] + dv1 * vw[(size_t)o0 * 259 + 257]
             + dv2 * vw[(size_t)o0 * 259 + 258] + vb[o0];
    float c1 = dv0 * vw[(size_t)o1 * 259 + 256] + dv1 * vw[(size_t)o1 * 259 + 257]
             + dv2 * vw[(size_t)o1 * 259 + 258] + vb[o1];
    int gi = 8 * NB + bidx;
    float g0 = G[gi * WD + o0],  g1 = G[gi * WD + o1];
    float e0 = Bt[gi * WD + o0], e1 = Bt[gi * WD + o1];
    __syncthreads();   // done reading hl (view GEMM + sigma head)
    #pragma unroll
    for (int m = 0; m < NS; m++){
      float2 hv;
      hv.x = sinf(g0 * (a0[m] + c0) + e0);
      hv.y = sinf(g1 * (a1[m] + c1) + e1);
      *(float2*)&hl[mb + m][o0] = hv;    // hl now holds feat
    }
    __syncthreads();
  }

  // ---- rgb head (reads feat) ----
  if (t < MP){
    float a0 = 0.f, a1 = 0.f, a2 = 0.f;
    #pragma unroll 4
    for (int q = 0; q < 64; q++){
      int qq = (q + t) & 63;
      float4 h4 = *(const float4*)&hl[t][qq * 4];
      float4 wA = *(const float4*)&rwl[0][qq * 4];
      float4 wB = *(const float4*)&rwl[1][qq * 4];
      float4 wC = *(const float4*)&rwl[2][qq * 4];
      a0 += h4.x * wA.x + h4.y * wA.y + h4.z * wA.z + h4.w * wA.w;
      a1 += h4.x * wB.x + h4.y * wB.y + h4.z * wB.z + h4.w * wB.w;
      a2 += h4.x * wC.x + h4.y * wC.y + h4.z * wC.z + h4.w * wC.w;
    }
    rgbl[t][0] = a0 + rgbb[0];
    rgbl[t][1] = a1 + rgbb[1];
    rgbl[t][2] = a2 + rgbb[2];
  }
  __syncthreads();

  // ---- volume integration weights + rgb_map (one thread per ray) ----
  if (t < RPB){
    int r = t;
    int ray = ray0 + r;
    float nr = nearv[bidx], fr = farv[bidx];
    float dnv = dn[r];
    float bet = sbeta[0];
    float vis = 1.f, wsum = 0.f, cr = 0.f, cg = 0.f, cb = 0.f;
    const float C = (1.0f - 1.0f / NS) / (NS - 1);
    #pragma unroll
    for (int s = 0; s < NS; s++){
      float w;
      if (s < NS - 1){
        float t0v = s * C, t1v = (s + 1) * C;
        float z0 = nr * (1.f - t0v) + fr * t0v;
        float z1 = nr * (1.f - t1v) + fr * t1v;
        float dist = (z1 - z0) * dnv;
        float sg = sigm(-sdfl[r * NS + s] / bet) / bet;
        float al = 1.f - expf(-sg * dist);
        w = al * vis;
        vis *= (1.f - al + 1e-10f);
        wsum += w;
      } else {
        w = 1.f - wsum;                 // force_background
      }
      wtl[r][s] = w;
      cr += w * sigm(rgbl[r * NS + s][0]);
      cg += w * sigm(rgbl[r * NS + s][1]);
      cb += w * sigm(rgbl[r * NS + s][2]);
    }
    size_t ob = (size_t)ray * 259;
    out[ob + 0] = -1.f + 2.f * cr;
    out[ob + 1] = -1.f + 2.f * cg;
    out[ob + 2] = -1.f + 2.f * cb;
  }
  __syncthreads();

  // ---- feature map: sum_s w_s * feat_s ----
  {
    float f0 = 0.f, f1 = 0.f;
    #pragma unroll
    for (int s = 0; s < NS; s++){
      float w = wtl[mg][s];
      float2 fv = *(const float2*)&hl[mb + s][o0];
      f0 = fmaf(w, fv.x, f0);
      f1 = fmaf(w, fv.y, f1);
    }
    size_t ob = (size_t)(ray0 + mg) * 259 + 3;
    out[ob + o0] = f0;
    out[ob + o1] = f1;
  }
}

extern "C" void kernel_launch(void* const* d_in, const int* in_sizes, int n_in,
                              void* d_out, int out_size, void* d_ws, size_t ws_size,
                              hipStream_t stream) {
  (void)in_sizes; (void)n_in; (void)out_size; (void)ws_size;
  const float* pose   = (const float*)d_in[0];
  const float* focal  = (const float*)d_in[1];
  const float* nearv  = (const float*)d_in[2];
  const float* farv   = (const float*)d_in[3];
  const float* styles = (const float*)d_in[4];
  const float* w0     = (const float*)d_in[5];
  const float* b0     = (const float*)d_in[6];
  const float* wsp    = (const float*)d_in[7];
  const float* bsp    = (const float*)d_in[8];
  const float* gw8    = (const float*)d_in[9];
  const float* gb8    = (const float*)d_in[10];
  const float* bw8    = (const float*)d_in[11];
  const float* bb8    = (const float*)d_in[12];
  const float* vw     = (const float*)d_in[13];
  const float* vb     = (const float*)d_in[14];
  const float* vgw    = (const float*)d_in[15];
  const float* vgb    = (const float*)d_in[16];
  const float* vbw    = (const float*)d_in[17];
  const float* vbb    = (const float*)d_in[18];
  const float* rgbw   = (const float*)d_in[19];
  const float* rgbb   = (const float*)d_in[20];
  const float* sgw    = (const float*)d_in[21];
  const float* sgb    = (const float*)d_in[22];
  const float* sbeta  = (const float*)d_in[23];

  float* G  = (float*)d_ws;
  float* Bt = G + 9 * NB * WD;
  float* out = (float*)d_out;

  film_kernel<<<dim3(18), dim3(256), 0, stream>>>(styles, gw8, gb8, bw8, bb8,
                                                  vgw, vgb, vbw, vbb, G, Bt);
  render_kernel<<<dim3(NBLK), dim3(NTH), 0, stream>>>(pose, focal, nearv, farv,
      w0, b0, wsp, bsp, vw, vb, rgbw, rgbb, sgw, sgb, sbeta, G, Bt, out);
}

// Round 4
// 855.224 us; speedup vs baseline: 5.1541x; 5.1541x over previous
//
#include <hip/hip_runtime.h>
#include <hip/hip_bf16.h>

#define RESN 64
#define NS 24
#define WD 256
#define SD 256
#define NB 2
#define RPB 4          // rays per block
#define MP 96          // points per block = RPB*NS
#define NTH 512
#define NBLK 2048      // (NB*RESN*RESN)/RPB

typedef unsigned short u16;
typedef unsigned int u32;
typedef __attribute__((ext_vector_type(8))) short short8v;   // 8 bf16 (4 VGPRs)
typedef __attribute__((ext_vector_type(16))) float f32x16;   // MFMA 32x32 accumulator

__device__ __forceinline__ float sigm(float x){ return 1.0f / (1.0f + expf(-x)); }

// range-reduced odd deg-9 sin, |x| <= ~100, abs err ~4e-6
__device__ __forceinline__ float fast_sin(float x){
  float k = __builtin_rintf(x * 0.31830988618f);
  float y = fmaf(k, -3.14159274101f, x);
  y = fmaf(k, 8.74227766e-8f, y);
  float y2 = y * y;
  float p = fmaf(y2, 2.75573192e-6f, -1.98412698e-4f);
  p = fmaf(y2, p, 8.33333333e-3f);
  p = fmaf(y2, p, -1.66666667e-1f);
  float s = fmaf(y * y2, p, y);
  u32 sg = ((u32)((int)k) & 1u) << 31;
  return __uint_as_float(__float_as_uint(s) ^ sg);
}

// ---------------- kernel 0: split fp32 weights into bf16 hi/lo planes ----------------
// layers 0..6 = hidden (wsp), layer 7 = view (first 256 cols of vw, stride 259)
__global__ void prep_kernel(const float* wsp, const float* vw, u16* Whi, u16* Wlo){
  int i0 = (blockIdx.x * 256 + threadIdx.x) * 4;
  #pragma unroll
  for (int j = 0; j < 4; j++){
    int e = i0 + j;
    int lay = e >> 16;
    int rk = e & 65535;
    float w = (lay < 7) ? wsp[lay * 65536 + rk]
                        : vw[(size_t)(rk >> 8) * 259 + (rk & 255)];
    u32 b = __float_as_uint(w);
    u16 hi = (u16)(b >> 16);
    float lof = w - __uint_as_float(b & 0xFFFF0000u);
    Whi[e] = hi;
    Wlo[e] = (u16)(__float_as_uint(lof) >> 16);
  }
}

// ---------------- kernel 1: FiLM gamma/beta per (layer, batch, out) ----------------
__global__ void film_kernel(const float* styles, const float* gw8, const float* gb8,
                            const float* bw8, const float* bb8,
                            const float* vgw, const float* vgb, const float* vbw, const float* vbb,
                            float* G, float* Bt){
  int l = blockIdx.x >> 1, b = blockIdx.x & 1, o = threadIdx.x;
  __shared__ float st[SD];
  st[o] = styles[b * SD + o];
  __syncthreads();
  const float *gw, *bw; float gbv, bbv;
  if (l < 8){
    gw = gw8 + ((size_t)l * WD + o) * SD; bw = bw8 + ((size_t)l * WD + o) * SD;
    gbv = gb8[l * WD + o];                bbv = bb8[l * WD + o];
  } else {
    gw = vgw + (size_t)o * SD;            bw = vbw + (size_t)o * SD;
    gbv = vgb[o];                         bbv = vbb[o];
  }
  float ag = 0.f, ab = 0.f;
  for (int s = 0; s < SD; s += 2){
    ag += st[s] * gw[s] + st[s+1] * gw[s+1];
    ab += st[s] * bw[s] + st[s+1] * bw[s+1];
  }
  int idx = (l * NB + b) * WD + o;
  G[idx]  = 15.0f * (ag + gbv) + 30.0f;
  Bt[idx] = 0.25f * (ab + bbv);
}

// ---------------- kernel 2: fused MFMA renderer ----------------
// 512 threads = 8 waves. Wave w owns output cols [w*32, w*32+32).
// H activations: two bf16 LDS planes (hi/lo), swizzled chunk = (col>>3)^(row&7).
#define KLOOP(LAY)                                                                 \
{ const u16* wph = Whi + (((size_t)(LAY) * WD + col) * WD) + khalf * 8;            \
  const u16* wpl = Wlo + (((size_t)(LAY) * WD + col) * WD) + khalf * 8;            \
  _Pragma("unroll 2")                                                              \
  for (int ks = 0; ks < 16; ks++){                                                 \
    short8v bh = *(const short8v*)(wph + ks * 16);                                 \
    short8v bl = *(const short8v*)(wpl + ks * 16);                                 \
    int ce = 2 * ks + khalf;                                                       \
    _Pragma("unroll")                                                              \
    for (int mt = 0; mt < 3; mt++){                                                \
      int elem = (mt * 32 + lane31) * WD + ((ce ^ l7) * 8);                        \
      short8v ah = *(const short8v*)(&Hhi[elem]);                                  \
      short8v al = *(const short8v*)(&Hlo[elem]);                                  \
      acc[mt] = __builtin_amdgcn_mfma_f32_32x32x16_bf16(ah, bh, acc[mt], 0, 0, 0); \
      acc[mt] = __builtin_amdgcn_mfma_f32_32x32x16_bf16(al, bh, acc[mt], 0, 0, 0); \
      acc[mt] = __builtin_amdgcn_mfma_f32_32x32x16_bf16(ah, bl, acc[mt], 0, 0, 0); \
    } } }

__launch_bounds__(NTH, 2)
__global__ void render_mfma(
    const float* pose, const float* focal, const float* nearv, const float* farv,
    const float* w0, const float* b0, const float* bsp,
    const float* vw, const float* vb,
    const float* rgbw, const float* rgbb, const float* sgw, const float* sgb,
    const float* sbeta, const float* G, const float* Bt,
    const u16* Whi, const u16* Wlo, float* out)
{
  __shared__ u16 Hhi[MP * WD];          // 48 KB
  __shared__ u16 Hlo[MP * WD];          // 48 KB
  __shared__ float xl[MP][4];
  __shared__ float vd[RPB][4];
  __shared__ float dn[RPB];
  __shared__ float sdfl[MP];
  __shared__ float rgbl[MP][4];
  __shared__ float wtl[RPB][NS];
  __shared__ float swl[WD];
  __shared__ float rwl[3][WD];

  const int t      = threadIdx.x;
  const int lane   = t & 63;
  const int wv     = t >> 6;
  const int lane31 = lane & 31;
  const int khalf  = lane >> 5;
  const int l7     = lane31 & 7;
  const int col    = wv * 32 + lane31;
  const int om     = t & 127;
  const int mg     = t >> 7;
  const int o0     = om * 2, o1 = om * 2 + 1;
  const int mb     = mg * NS;
  const int ray0   = blockIdx.x * RPB;
  const int bidx   = ray0 >> 12;

  if (t < WD) swl[t] = sgw[t];
  for (int i = t; i < 3 * WD; i += NTH) ((float*)rwl)[i] = rgbw[i];

  // ---- point setup ----
  if (t < MP){
    int m = t, s = m % NS, rl = m / NS;
    int ray = ray0 + rl;
    int ww = ray & (RESN - 1);
    int hh = (ray >> 6) & (RESN - 1);
    float f = focal[bidx], nr = nearv[bidx], fr = farv[bidx];
    float di = ((ww + 0.5f) - RESN * 0.5f) / f;
    float dj = -(((hh + 0.5f) - RESN * 0.5f) / f);
    const float* P = pose + bidx * 12;
    float rdx = di * P[0] + dj * P[1] - P[2];
    float rdy = di * P[4] + dj * P[5] - P[6];
    float rdz = di * P[8] + dj * P[9] - P[10];
    float ox = P[3], oy = P[7], oz = P[11];
    float nrm = sqrtf(rdx * rdx + rdy * rdy + rdz * rdz);
    const float C = (1.0f - 1.0f / NS) / (NS - 1);
    float tv = s * C;
    float z = nr * (1.0f - tv) + fr * tv;
    float sc = 2.0f / (fr - nr);
    xl[m][0] = (ox + rdx * z) * sc;
    xl[m][1] = (oy + rdy * z) * sc;
    xl[m][2] = (oz + rdz * z) * sc;
    if (s == 0){
      vd[rl][0] = rdx / nrm; vd[rl][1] = rdy / nrm; vd[rl][2] = rdz / nrm;
      dn[rl] = nrm;
    }
  }
  __syncthreads();

  // ---- layer 0: 3 -> 256 (VALU), writes bf16 hi/lo planes ----
  {
    float wa[3], wbv[3];
    #pragma unroll
    for (int j = 0; j < 3; j++){ wa[j] = w0[o0 * 3 + j]; wbv[j] = w0[o1 * 3 + j]; }
    float bi0 = b0[o0], bi1 = b0[o1];
    float g0 = G[bidx * WD + o0],  g1 = G[bidx * WD + o1];
    float e0 = Bt[bidx * WD + o0], e1 = Bt[bidx * WD + o1];
    #pragma unroll
    for (int m = 0; m < NS; m++){
      int row = mb + m;
      float x0 = xl[row][0], x1 = xl[row][1], x2 = xl[row][2];
      float u0 = x0 * wa[0]  + x1 * wa[1]  + x2 * wa[2]  + bi0;
      float u1 = x0 * wbv[0] + x1 * wbv[1] + x2 * wbv[2] + bi1;
      float s0 = fast_sin(fmaf(g0, u0, e0));
      float s1 = fast_sin(fmaf(g1, u1, e1));
      u32 bs0 = __float_as_uint(s0), bs1 = __float_as_uint(s1);
      u32 hw = (bs0 >> 16) | (bs1 & 0xFFFF0000u);
      float l0f = s0 - __uint_as_float(bs0 & 0xFFFF0000u);
      float l1f = s1 - __uint_as_float(bs1 & 0xFFFF0000u);
      u32 lw = (__float_as_uint(l0f) >> 16) | (__float_as_uint(l1f) & 0xFFFF0000u);
      int eidx = row * WD + (((o0 >> 3) ^ (row & 7)) * 8) + (o0 & 7);
      *(u32*)&Hhi[eidx] = hw;
      *(u32*)&Hlo[eidx] = lw;
    }
  }
  __syncthreads();

  // ---- 7 hidden layers via MFMA ----
  #pragma unroll 1
  for (int l = 0; l < 7; l++){
    f32x16 acc[3];
    #pragma unroll
    for (int mt = 0; mt < 3; mt++)
      #pragma unroll
      for (int j = 0; j < 16; j++) acc[mt][j] = 0.f;
    KLOOP(l)
    float g  = G[((l + 1) * NB + bidx) * WD + col];
    float e  = Bt[((l + 1) * NB + bidx) * WD + col];
    float bi = bsp[l * WD + col];
    __syncthreads();
    #pragma unroll
    for (int mt = 0; mt < 3; mt++){
      #pragma unroll
      for (int rg = 0; rg < 16; rg++){
        int row = mt * 32 + (rg & 3) + 8 * (rg >> 2) + 4 * khalf;
        float a = acc[mt][rg] + bi;
        float s = fast_sin(fmaf(g, a, e));
        u32 sb = __float_as_uint(s);
        int eidx = row * WD + ((((col >> 3) ^ (row & 7))) * 8) + (col & 7);
        Hhi[eidx] = (u16)(sb >> 16);
        float sl = s - __uint_as_float(sb & 0xFFFF0000u);
        Hlo[eidx] = (u16)(__float_as_uint(sl) >> 16);
      }
    }
    __syncthreads();
  }

  // ---- view layer K-loop (lay 7 of planes) ----
  f32x16 acc[3];
  #pragma unroll
  for (int mt = 0; mt < 3; mt++)
    #pragma unroll
    for (int j = 0; j < 16; j++) acc[mt][j] = 0.f;
  KLOOP(7)
  // view tail weights (cols 256..258) + bias, per output col
  float vt0 = vw[(size_t)col * 259 + 256];
  float vt1 = vw[(size_t)col * 259 + 257];
  float vt2 = vw[(size_t)col * 259 + 258];
  float vbv = vb[col];
  float gv = G[(8 * NB + bidx) * WD + col];
  float ev = Bt[(8 * NB + bidx) * WD + col];

  // ---- sigma head (reads layer-7 planes, before epilogue overwrites) ----
  if (t < MP){
    float a = 0.f;
    #pragma unroll 4
    for (int c = 0; c < 32; c++){
      int eb = t * WD + ((c ^ (t & 7)) * 8);
      short8v hv = *(const short8v*)(&Hhi[eb]);
      short8v lv = *(const short8v*)(&Hlo[eb]);
      #pragma unroll
      for (int j = 0; j < 8; j++){
        float h = __uint_as_float(((u32)(u16)hv[j]) << 16)
                + __uint_as_float(((u32)(u16)lv[j]) << 16);
        a = fmaf(h, swl[c * 8 + j], a);
      }
    }
    sdfl[t] = a + sgb[0];
  }
  __syncthreads();

  // ---- view epilogue: feat = sin(g*(acc + dir-term) + e) -> planes ----
  #pragma unroll
  for (int mt = 0; mt < 3; mt++){
    #pragma unroll
    for (int rg = 0; rg < 16; rg++){
      int row = mt * 32 + (rg & 3) + 8 * (rg >> 2) + 4 * khalf;
      int ray = (row >= 48) ? ((row >= 72) ? 3 : 2) : ((row >= 24) ? 1 : 0);
      float c = vd[ray][0] * vt0 + vd[ray][1] * vt1 + vd[ray][2] * vt2 + vbv;
      float a = acc[mt][rg] + c;
      float s = fast_sin(fmaf(gv, a, ev));
      u32 sb = __float_as_uint(s);
      int eidx = row * WD + ((((col >> 3) ^ (row & 7))) * 8) + (col & 7);
      Hhi[eidx] = (u16)(sb >> 16);
      float sl = s - __uint_as_float(sb & 0xFFFF0000u);
      Hlo[eidx] = (u16)(__float_as_uint(sl) >> 16);
    }
  }
  __syncthreads();

  // ---- rgb head (reads feat planes) ----
  if (t < MP){
    float a0 = 0.f, a1 = 0.f, a2 = 0.f;
    #pragma unroll 4
    for (int c = 0; c < 32; c++){
      int eb = t * WD + ((c ^ (t & 7)) * 8);
      short8v hv = *(const short8v*)(&Hhi[eb]);
      short8v lv = *(const short8v*)(&Hlo[eb]);
      #pragma unroll
      for (int j = 0; j < 8; j++){
        float h = __uint_as_float(((u32)(u16)hv[j]) << 16)
                + __uint_as_float(((u32)(u16)lv[j]) << 16);
        int k = c * 8 + j;
        a0 = fmaf(h, rwl[0][k], a0);
        a1 = fmaf(h, rwl[1][k], a1);
        a2 = fmaf(h, rwl[2][k], a2);
      }
    }
    rgbl[t][0] = a0 + rgbb[0];
    rgbl[t][1] = a1 + rgbb[1];
    rgbl[t][2] = a2 + rgbb[2];
  }
  __syncthreads();

  // ---- volume integration weights + rgb_map (one thread per ray) ----
  if (t < RPB){
    int r = t;
    int ray = ray0 + r;
    float nr = nearv[bidx], fr = farv[bidx];
    float dnv = dn[r];
    float bet = sbeta[0];
    float vis = 1.f, wsum = 0.f, cr = 0.f, cg = 0.f, cb = 0.f;
    const float C = (1.0f - 1.0f / NS) / (NS - 1);
    #pragma unroll
    for (int s = 0; s < NS; s++){
      float w;
      if (s < NS - 1){
        float t0v = s * C, t1v = (s + 1) * C;
        float z0 = nr * (1.f - t0v) + fr * t0v;
        float z1 = nr * (1.f - t1v) + fr * t1v;
        float dist = (z1 - z0) * dnv;
        float sg = sigm(-sdfl[r * NS + s] / bet) / bet;
        float al = 1.f - expf(-sg * dist);
        w = al * vis;
        vis *= (1.f - al + 1e-10f);
        wsum += w;
      } else {
        w = 1.f - wsum;
      }
      wtl[r][s] = w;
      cr += w * sigm(rgbl[r * NS + s][0]);
      cg += w * sigm(rgbl[r * NS + s][1]);
      cb += w * sigm(rgbl[r * NS + s][2]);
    }
    size_t ob = (size_t)ray * 259;
    out[ob + 0] = -1.f + 2.f * cr;
    out[ob + 1] = -1.f + 2.f * cg;
    out[ob + 2] = -1.f + 2.f * cb;
  }
  __syncthreads();

  // ---- feature map: sum_s w_s * feat_s ----
  {
    float f0 = 0.f, f1 = 0.f;
    #pragma unroll
    for (int s = 0; s < NS; s++){
      int row = mb + s;
      float w = wtl[mg][s];
      int eidx = row * WD + (((o0 >> 3) ^ (row & 7)) * 8) + (o0 & 7);
      u32 wh = *(const u32*)&Hhi[eidx];
      u32 wl = *(const u32*)&Hlo[eidx];
      float fa = __uint_as_float(wh << 16) + __uint_as_float(wl << 16);
      float fb = __uint_as_float(wh & 0xFFFF0000u) + __uint_as_float(wl & 0xFFFF0000u);
      f0 = fmaf(w, fa, f0);
      f1 = fmaf(w, fb, f1);
    }
    size_t ob = (size_t)(ray0 + mg) * 259 + 3;
    out[ob + o0] = f0;
    out[ob + o1] = f1;
  }
}

// ---------------- fallback: round-3 fp32 VALU renderer (used if ws too small) ----------------
__launch_bounds__(NTH, 2)
__global__ void render_kernel(
    const float* pose, const float* focal, const float* nearv, const float* farv,
    const float* w0, const float* b0, const float* wsp, const float* bsp,
    const float* vw, const float* vb,
    const float* rgbw, const float* rgbb, const float* sgw, const float* sgb,
    const float* sbeta, const float* G, const float* Bt, float* out)
{
  __shared__ float hl[MP][WD];
  __shared__ float xl[MP][4];
  __shared__ float vd[RPB][4];
  __shared__ float dn[RPB];
  __shared__ float sdfl[MP];
  __shared__ float rgbl[MP][4];
  __shared__ float wtl[RPB][NS];
  __shared__ float swl[WD];
  __shared__ float rwl[3][WD];

  const int t   = threadIdx.x;
  const int om  = t & 127;
  const int mg  = t >> 7;
  const int o0  = om * 2, o1 = om * 2 + 1;
  const int mb  = mg * NS;
  const int ray0 = blockIdx.x * RPB;
  const int bidx = ray0 >> 12;

  if (t < WD) swl[t] = sgw[t];
  for (int i = t; i < 3 * WD; i += NTH) ((float*)rwl)[i] = rgbw[i];

  if (t < MP){
    int m = t, s = m % NS, rl = m / NS;
    int ray = ray0 + rl;
    int ww = ray & (RESN - 1);
    int hh = (ray >> 6) & (RESN - 1);
    float f = focal[bidx], nr = nearv[bidx], fr = farv[bidx];
    float di = ((ww + 0.5f) - RESN * 0.5f) / f;
    float dj = -(((hh + 0.5f) - RESN * 0.5f) / f);
    const float* P = pose + bidx * 12;
    float rdx = di * P[0] + dj * P[1] - P[2];
    float rdy = di * P[4] + dj * P[5] - P[6];
    float rdz = di * P[8] + dj * P[9] - P[10];
    float ox = P[3], oy = P[7], oz = P[11];
    float nrm = sqrtf(rdx * rdx + rdy * rdy + rdz * rdz);
    const float C = (1.0f - 1.0f / NS) / (NS - 1);
    float tv = s * C;
    float z = nr * (1.0f - tv) + fr * tv;
    float sc = 2.0f / (fr - nr);
    xl[m][0] = (ox + rdx * z) * sc;
    xl[m][1] = (oy + rdy * z) * sc;
    xl[m][2] = (oz + rdz * z) * sc;
    if (s == 0){
      vd[rl][0] = rdx / nrm; vd[rl][1] = rdy / nrm; vd[rl][2] = rdz / nrm;
      dn[rl] = nrm;
    }
  }
  __syncthreads();

  {
    float wa[3], wbv[3];
    #pragma unroll
    for (int j = 0; j < 3; j++){ wa[j] = w0[o0 * 3 + j]; wbv[j] = w0[o1 * 3 + j]; }
    float bi0 = b0[o0], bi1 = b0[o1];
    float g0 = G[bidx * WD + o0],  g1 = G[bidx * WD + o1];
    float e0 = Bt[bidx * WD + o0], e1 = Bt[bidx * WD + o1];
    #pragma unroll
    for (int m = 0; m < NS; m++){
      float x0 = xl[mb + m][0], x1 = xl[mb + m][1], x2 = xl[mb + m][2];
      float u0 = x0 * wa[0]  + x1 * wa[1]  + x2 * wa[2]  + bi0;
      float u1 = x0 * wbv[0] + x1 * wbv[1] + x2 * wbv[2] + bi1;
      float2 hv; hv.x = fast_sin(g0 * u0 + e0); hv.y = fast_sin(g1 * u1 + e1);
      *(float2*)&hl[mb + m][o0] = hv;
    }
  }
  __syncthreads();

  #pragma unroll 1
  for (int l = 0; l < 7; l++){
    const float* wl = wsp + (size_t)l * WD * WD;
    float a0[NS], a1[NS];
    #pragma unroll
    for (int m = 0; m < NS; m++){ a0[m] = 0.f; a1[m] = 0.f; }
    #pragma unroll 1
    for (int kc = 0; kc < 8; kc++){
      float wr0[32], wr1[32];
      const float4* p0 = (const float4*)(wl + (size_t)o0 * WD + kc * 32);
      const float4* p1 = (const float4*)(wl + (size_t)o1 * WD + kc * 32);
      #pragma unroll
      for (int q = 0; q < 8; q++){
        float4 u0 = p0[q], u1 = p1[q];
        wr0[q*4+0] = u0.x; wr0[q*4+1] = u0.y; wr0[q*4+2] = u0.z; wr0[q*4+3] = u0.w;
        wr1[q*4+0] = u1.x; wr1[q*4+1] = u1.y; wr1[q*4+2] = u1.z; wr1[q*4+3] = u1.w;
      }
      #pragma unroll
      for (int m = 0; m < NS; m++){
        const float4* hp = (const float4*)&hl[mb + m][kc * 32];
        #pragma unroll
        for (int q = 0; q < 8; q++){
          float4 h4 = hp[q];
          a0[m] = fmaf(h4.x, wr0[q*4+0], a0[m]);
          a0[m] = fmaf(h4.y, wr0[q*4+1], a0[m]);
          a0[m] = fmaf(h4.z, wr0[q*4+2], a0[m]);
          a0[m] = fmaf(h4.w, wr0[q*4+3], a0[m]);
          a1[m] = fmaf(h4.x, wr1[q*4+0], a1[m]);
          a1[m] = fmaf(h4.y, wr1[q*4+1], a1[m]);
          a1[m] = fmaf(h4.z, wr1[q*4+2], a1[m]);
          a1[m] = fmaf(h4.w, wr1[q*4+3], a1[m]);
        }
      }
    }
    int gi = (l + 1) * NB + bidx;
    float g0 = G[gi * WD + o0],  g1 = G[gi * WD + o1];
    float e0 = Bt[gi * WD + o0], e1 = Bt[gi * WD + o1];
    float bi0 = bsp[l * WD + o0], bi1 = bsp[l * WD + o1];
    __syncthreads();
    #pragma unroll
    for (int m = 0; m < NS; m++){
      float2 hv;
      hv.x = fast_sin(g0 * (a0[m] + bi0) + e0);
      hv.y = fast_sin(g1 * (a1[m] + bi1) + e1);
      *(float2*)&hl[mb + m][o0] = hv;
    }
    __syncthreads();
  }

  if (t < MP){
    float a = 0.f;
    #pragma unroll 4
    for (int q = 0; q < 64; q++){
      int qq = (q + t) & 63;
      float4 h4 = *(const float4*)&hl[t][qq * 4];
      float4 w4 = *(const float4*)&swl[qq * 4];
      a += h4.x * w4.x + h4.y * w4.y + h4.z * w4.z + h4.w * w4.w;
    }
    sdfl[t] = a + sgb[0];
  }

  {
    float a0[NS], a1[NS];
    #pragma unroll
    for (int m = 0; m < NS; m++){ a0[m] = 0.f; a1[m] = 0.f; }
    #pragma unroll 1
    for (int kc = 0; kc < 8; kc++){
      float wr0[32], wr1[32];
      const float* r0 = vw + (size_t)o0 * 259 + kc * 32;
      const float* r1 = vw + (size_t)o1 * 259 + kc * 32;
      #pragma unroll
      for (int j = 0; j < 32; j += 2){
        float2 v0 = *(const float2*)(r0 + j);
        wr0[j] = v0.x; wr0[j+1] = v0.y;
      }
      #pragma unroll
      for (int j = 0; j < 32; j++){ wr1[j] = r1[j]; }
      #pragma unroll
      for (int m = 0; m < NS; m++){
        const float4* hp = (const float4*)&hl[mb + m][kc * 32];
        #pragma unroll
        for (int q = 0; q < 8; q++){
          float4 h4 = hp[q];
          a0[m] = fmaf(h4.x, wr0[q*4+0], a0[m]);
          a0[m] = fmaf(h4.y, wr0[q*4+1], a0[m]);
          a0[m] = fmaf(h4.z, wr0[q*4+2], a0[m]);
          a0[m] = fmaf(h4.w, wr0[q*4+3], a0[m]);
          a1[m] = fmaf(h4.x, wr1[q*4+0], a1[m]);
          a1[m] = fmaf(h4.y, wr1[q*4+1], a1[m]);
          a1[m] = fmaf(h4.z, wr1[q*4+2], a1[m]);
          a1[m] = fmaf(h4.w, wr1[q*4+3], a1[m]);
        }
      }
    }
    float dv0 = vd[mg][0], dv1 = vd[mg][1], dv2 = vd[mg][2];
    float c0 = dv0 * vw[(size_t)o0 * 259 + 256] + dv1 * vw[(size_t)o0 * 259 + 257]
             + dv2 * vw[(size_t)o0 * 259 + 258] + vb[o0];
    float c1 = dv0 * vw[(size_t)o1 * 259 + 256] + dv1 * vw[(size_t)o1 * 259 + 257]
             + dv2 * vw[(size_t)o1 * 259 + 258] + vb[o1];
    int gi = 8 * NB + bidx;
    float g0 = G[gi * WD + o0],  g1 = G[gi * WD + o1];
    float e0 = Bt[gi * WD + o0], e1 = Bt[gi * WD + o1];
    __syncthreads();
    #pragma unroll
    for (int m = 0; m < NS; m++){
      float2 hv;
      hv.x = fast_sin(g0 * (a0[m] + c0) + e0);
      hv.y = fast_sin(g1 * (a1[m] + c1) + e1);
      *(float2*)&hl[mb + m][o0] = hv;
    }
    __syncthreads();
  }

  if (t < MP){
    float a0 = 0.f, a1 = 0.f, a2 = 0.f;
    #pragma unroll 4
    for (int q = 0; q < 64; q++){
      int qq = (q + t) & 63;
      float4 h4 = *(const float4*)&hl[t][qq * 4];
      float4 wA = *(const float4*)&rwl[0][qq * 4];
      float4 wB = *(const float4*)&rwl[1][qq * 4];
      float4 wC = *(const float4*)&rwl[2][qq * 4];
      a0 += h4.x * wA.x + h4.y * wA.y + h4.z * wA.z + h4.w * wA.w;
      a1 += h4.x * wB.x + h4.y * wB.y + h4.z * wB.z + h4.w * wB.w;
      a2 += h4.x * wC.x + h4.y * wC.y + h4.z * wC.z + h4.w * wC.w;
    }
    rgbl[t][0] = a0 + rgbb[0];
    rgbl[t][1] = a1 + rgbb[1];
    rgbl[t][2] = a2 + rgbb[2];
  }
  __syncthreads();

  if (t < RPB){
    int r = t;
    int ray = ray0 + r;
    float nr = nearv[bidx], fr = farv[bidx];
    float dnv = dn[r];
    float bet = sbeta[0];
    float vis = 1.f, wsum = 0.f, cr = 0.f, cg = 0.f, cb = 0.f;
    const float C = (1.0f - 1.0f / NS) / (NS - 1);
    #pragma unroll
    for (int s = 0; s < NS; s++){
      float w;
      if (s < NS - 1){
        float t0v = s * C, t1v = (s + 1) * C;
        float z0 = nr * (1.f - t0v) + fr * t0v;
        float z1 = nr * (1.f - t1v) + fr * t1v;
        float dist = (z1 - z0) * dnv;
        float sg = sigm(-sdfl[r * NS + s] / bet) / bet;
        float al = 1.f - expf(-sg * dist);
        w = al * vis;
        vis *= (1.f - al + 1e-10f);
        wsum += w;
      } else {
        w = 1.f - wsum;
      }
      wtl[r][s] = w;
      cr += w * sigm(rgbl[r * NS + s][0]);
      cg += w * sigm(rgbl[r * NS + s][1]);
      cb += w * sigm(rgbl[r * NS + s][2]);
    }
    size_t ob = (size_t)ray * 259;
    out[ob + 0] = -1.f + 2.f * cr;
    out[ob + 1] = -1.f + 2.f * cg;
    out[ob + 2] = -1.f + 2.f * cb;
  }
  __syncthreads();

  {
    float f0 = 0.f, f1 = 0.f;
    #pragma unroll
    for (int s = 0; s < NS; s++){
      float w = wtl[mg][s];
      float2 fv = *(const float2*)&hl[mb + s][o0];
      f0 = fmaf(w, fv.x, f0);
      f1 = fmaf(w, fv.y, f1);
    }
    size_t ob = (size_t)(ray0 + mg) * 259 + 3;
    out[ob + o0] = f0;
    out[ob + o1] = f1;
  }
}

extern "C" void kernel_launch(void* const* d_in, const int* in_sizes, int n_in,
                              void* d_out, int out_size, void* d_ws, size_t ws_size,
                              hipStream_t stream) {
  (void)in_sizes; (void)n_in; (void)out_size;
  const float* pose   = (const float*)d_in[0];
  const float* focal  = (const float*)d_in[1];
  const float* nearv  = (const float*)d_in[2];
  const float* farv   = (const float*)d_in[3];
  const float* styles = (const float*)d_in[4];
  const float* w0     = (const float*)d_in[5];
  const float* b0     = (const float*)d_in[6];
  const float* wsp    = (const float*)d_in[7];
  const float* bsp    = (const float*)d_in[8];
  const float* gw8    = (const float*)d_in[9];
  const float* gb8    = (const float*)d_in[10];
  const float* bw8    = (const float*)d_in[11];
  const float* bb8    = (const float*)d_in[12];
  const float* vw     = (const float*)d_in[13];
  const float* vb     = (const float*)d_in[14];
  const float* vgw    = (const float*)d_in[15];
  const float* vgb    = (const float*)d_in[16];
  const float* vbw    = (const float*)d_in[17];
  const float* vbb    = (const float*)d_in[18];
  const float* rgbw   = (const float*)d_in[19];
  const float* rgbb   = (const float*)d_in[20];
  const float* sgw    = (const float*)d_in[21];
  const float* sgb    = (const float*)d_in[22];
  const float* sbeta  = (const float*)d_in[23];

  float* G  = (float*)d_ws;
  float* Bt = G + 9 * NB * WD;                       // 4608 floats
  float* out = (float*)d_out;

  const size_t plane_off = 36864;                    // bytes (G+Bt)
  const size_t plane_elems = (size_t)8 * WD * WD;    // 524288 u16 per plane
  const size_t need = plane_off + 2 * plane_elems * sizeof(u16);

  film_kernel<<<dim3(18), dim3(256), 0, stream>>>(styles, gw8, gb8, bw8, bb8,
                                                  vgw, vgb, vbw, vbb, G, Bt);
  if (ws_size >= need){
    u16* Whi = (u16*)((char*)d_ws + plane_off);
    u16* Wlo = Whi + plane_elems;
    prep_kernel<<<dim3(512), dim3(256), 0, stream>>>(wsp, vw, Whi, Wlo);
    render_mfma<<<dim3(NBLK), dim3(NTH), 0, stream>>>(pose, focal, nearv, farv,
        w0, b0, bsp, vw, vb, rgbw, rgbb, sgw, sgb, sbeta, G, Bt, Whi, Wlo, out);
  } else {
    render_kernel<<<dim3(NBLK), dim3(NTH), 0, stream>>>(pose, focal, nearv, farv,
        w0, b0, wsp, bsp, vw, vb, rgbw, rgbb, sgw, sgb, sbeta, G, Bt, out);
  }
}

// Round 5
// 844.224 us; speedup vs baseline: 5.2212x; 1.0130x over previous
//
#include <hip/hip_runtime.h>
#include <hip/hip_bf16.h>

#define RESN 64
#define NS 24
#define WD 256
#define SD 256
#define NB 2
#define RPB 4          // rays per block
#define MP 96          // points per block = RPB*NS
#define NTH 512
#define NBLK 2048      // (NB*RESN*RESN)/RPB

typedef unsigned short u16;
typedef unsigned int u32;
typedef __attribute__((ext_vector_type(8))) short short8v;   // 8 bf16 (4 VGPRs)
typedef __attribute__((ext_vector_type(16))) float f32x16;   // MFMA 32x32 accumulator

__device__ __forceinline__ float sigm(float x){ return 1.0f / (1.0f + expf(-x)); }

// range-reduced odd deg-9 sin, |x| <= ~100, abs err ~4e-6
__device__ __forceinline__ float fast_sin(float x){
  float k = __builtin_rintf(x * 0.31830988618f);
  float y = fmaf(k, -3.14159274101f, x);
  y = fmaf(k, 8.74227766e-8f, y);
  float y2 = y * y;
  float p = fmaf(y2, 2.75573192e-6f, -1.98412698e-4f);
  p = fmaf(y2, p, 8.33333333e-3f);
  p = fmaf(y2, p, -1.66666667e-1f);
  float s = fmaf(y * y2, p, y);
  u32 sg = ((u32)((int)k) & 1u) << 31;
  return __uint_as_float(__float_as_uint(s) ^ sg);
}

// ---------------- kernel 0: split fp32 weights into bf16 hi/lo planes ----------------
// layers 0..6 = hidden (wsp), layer 7 = view (first 256 cols of vw, stride 259)
__global__ void prep_kernel(const float* wsp, const float* vw, u16* Whi, u16* Wlo){
  int i0 = (blockIdx.x * 256 + threadIdx.x) * 4;
  #pragma unroll
  for (int j = 0; j < 4; j++){
    int e = i0 + j;
    int lay = e >> 16;
    int rk = e & 65535;
    float w = (lay < 7) ? wsp[lay * 65536 + rk]
                        : vw[(size_t)(rk >> 8) * 259 + (rk & 255)];
    u32 b = __float_as_uint(w);
    u16 hi = (u16)(b >> 16);
    float lof = w - __uint_as_float(b & 0xFFFF0000u);
    Whi[e] = hi;
    Wlo[e] = (u16)(__float_as_uint(lof) >> 16);
  }
}

// ---------------- kernel 1: FiLM gamma/beta per (layer, batch, out) ----------------
__global__ void film_kernel(const float* styles, const float* gw8, const float* gb8,
                            const float* bw8, const float* bb8,
                            const float* vgw, const float* vgb, const float* vbw, const float* vbb,
                            float* G, float* Bt){
  int l = blockIdx.x >> 1, b = blockIdx.x & 1, o = threadIdx.x;
  __shared__ float st[SD];
  st[o] = styles[b * SD + o];
  __syncthreads();
  const float *gw, *bw; float gbv, bbv;
  if (l < 8){
    gw = gw8 + ((size_t)l * WD + o) * SD; bw = bw8 + ((size_t)l * WD + o) * SD;
    gbv = gb8[l * WD + o];                bbv = bb8[l * WD + o];
  } else {
    gw = vgw + (size_t)o * SD;            bw = vbw + (size_t)o * SD;
    gbv = vgb[o];                         bbv = vbb[o];
  }
  float ag = 0.f, ab = 0.f;
  for (int s = 0; s < SD; s += 2){
    ag += st[s] * gw[s] + st[s+1] * gw[s+1];
    ab += st[s] * bw[s] + st[s+1] * bw[s+1];
  }
  int idx = (l * NB + b) * WD + o;
  G[idx]  = 15.0f * (ag + gbv) + 30.0f;
  Bt[idx] = 0.25f * (ab + bbv);
}

// ---------------- kernel 2: fused MFMA renderer ----------------
// 512 threads = 8 waves. Wave w owns output cols [w*32, w*32+32).
// H activations: two bf16 LDS planes (hi/lo), swizzled chunk = (col>>3)^(row&7).
// B-operand: depth-4 rolling register prefetch; each layer's first 4 chunks are
// issued during the previous layer's epilogue (cross-barrier prefetch).
#define SETW(LAY) { wph = Whi + (((size_t)(LAY) * WD + col) * WD) + khalf * 8;   \
                    wpl = Wlo + (((size_t)(LAY) * WD + col) * WD) + khalf * 8; }

#define PREF4 { _Pragma("unroll")                                                \
  for (int i = 0; i < 4; i++){                                                   \
    pbh[i] = *(const short8v*)(wph + i * 16);                                    \
    pbl[i] = *(const short8v*)(wpl + i * 16); } }

#define KMAIN                                                                    \
  _Pragma("unroll")                                                              \
  for (int ks = 0; ks < 16; ks++){                                               \
    short8v bh = pbh[ks & 3], bl = pbl[ks & 3];                                  \
    if (ks < 12){ pbh[ks & 3] = *(const short8v*)(wph + (ks + 4) * 16);          \
                  pbl[ks & 3] = *(const short8v*)(wpl + (ks + 4) * 16); }        \
    int ce = 2 * ks + khalf;                                                     \
    _Pragma("unroll")                                                            \
    for (int mt = 0; mt < 3; mt++){                                              \
      int elem = (mt * 32 + lane31) * WD + ((ce ^ l7) * 8);                      \
      short8v ah = *(const short8v*)(&Hhi[elem]);                                \
      short8v al = *(const short8v*)(&Hlo[elem]);                                \
      acc[mt] = __builtin_amdgcn_mfma_f32_32x32x16_bf16(ah, bh, acc[mt], 0,0,0); \
      acc[mt] = __builtin_amdgcn_mfma_f32_32x32x16_bf16(al, bh, acc[mt], 0,0,0); \
      acc[mt] = __builtin_amdgcn_mfma_f32_32x32x16_bf16(ah, bl, acc[mt], 0,0,0); \
    } }

__launch_bounds__(NTH, 2)
__global__ void render_mfma(
    const float* pose, const float* focal, const float* nearv, const float* farv,
    const float* w0, const float* b0, const float* bsp,
    const float* vw, const float* vb,
    const float* rgbw, const float* rgbb, const float* sgw, const float* sgb,
    const float* sbeta, const float* G, const float* Bt,
    const u16* Whi, const u16* Wlo, float* out)
{
  __shared__ u16 Hhi[MP * WD];          // 48 KB
  __shared__ u16 Hlo[MP * WD];          // 48 KB
  __shared__ float xl[MP][4];
  __shared__ float vd[RPB][4];
  __shared__ float dn[RPB];
  __shared__ float sdfl[MP];
  __shared__ float rgbl[MP][4];
  __shared__ float wtl[RPB][NS];
  __shared__ float swl[WD];
  __shared__ float rwl[3][WD];

  const int t      = threadIdx.x;
  const int lane   = t & 63;
  const int wv     = t >> 6;
  const int lane31 = lane & 31;
  const int khalf  = lane >> 5;
  const int l7     = lane31 & 7;
  const int col    = wv * 32 + lane31;
  const int om     = t & 127;
  const int mg     = t >> 7;
  const int o0     = om * 2, o1 = om * 2 + 1;
  const int mb     = mg * NS;
  const int ray0   = blockIdx.x * RPB;
  const int bidx   = ray0 >> 12;

  // B prefetch state (persists across layers)
  const u16 *wph, *wpl;
  short8v pbh[4], pbl[4];
  SETW(0); PREF4;                      // layer-0 weights fly during setup

  if (t < WD) swl[t] = sgw[t];
  for (int i = t; i < 3 * WD; i += NTH) ((float*)rwl)[i] = rgbw[i];

  // ---- point setup ----
  if (t < MP){
    int m = t, s = m % NS, rl = m / NS;
    int ray = ray0 + rl;
    int ww = ray & (RESN - 1);
    int hh = (ray >> 6) & (RESN - 1);
    float f = focal[bidx], nr = nearv[bidx], fr = farv[bidx];
    float di = ((ww + 0.5f) - RESN * 0.5f) / f;
    float dj = -(((hh + 0.5f) - RESN * 0.5f) / f);
    const float* P = pose + bidx * 12;
    float rdx = di * P[0] + dj * P[1] - P[2];
    float rdy = di * P[4] + dj * P[5] - P[6];
    float rdz = di * P[8] + dj * P[9] - P[10];
    float ox = P[3], oy = P[7], oz = P[11];
    float nrm = sqrtf(rdx * rdx + rdy * rdy + rdz * rdz);
    const float C = (1.0f - 1.0f / NS) / (NS - 1);
    float tv = s * C;
    float z = nr * (1.0f - tv) + fr * tv;
    float sc = 2.0f / (fr - nr);
    xl[m][0] = (ox + rdx * z) * sc;
    xl[m][1] = (oy + rdy * z) * sc;
    xl[m][2] = (oz + rdz * z) * sc;
    if (s == 0){
      vd[rl][0] = rdx / nrm; vd[rl][1] = rdy / nrm; vd[rl][2] = rdz / nrm;
      dn[rl] = nrm;
    }
  }
  __syncthreads();

  // ---- layer 0: 3 -> 256 (VALU), writes bf16 hi/lo planes ----
  {
    float wa[3], wbv[3];
    #pragma unroll
    for (int j = 0; j < 3; j++){ wa[j] = w0[o0 * 3 + j]; wbv[j] = w0[o1 * 3 + j]; }
    float bi0 = b0[o0], bi1 = b0[o1];
    float g0 = G[bidx * WD + o0],  g1 = G[bidx * WD + o1];
    float e0 = Bt[bidx * WD + o0], e1 = Bt[bidx * WD + o1];
    #pragma unroll
    for (int m = 0; m < NS; m++){
      int row = mb + m;
      float x0 = xl[row][0], x1 = xl[row][1], x2 = xl[row][2];
      float u0 = x0 * wa[0]  + x1 * wa[1]  + x2 * wa[2]  + bi0;
      float u1 = x0 * wbv[0] + x1 * wbv[1] + x2 * wbv[2] + bi1;
      float s0 = fast_sin(fmaf(g0, u0, e0));
      float s1 = fast_sin(fmaf(g1, u1, e1));
      u32 bs0 = __float_as_uint(s0), bs1 = __float_as_uint(s1);
      u32 hw = (bs0 >> 16) | (bs1 & 0xFFFF0000u);
      float l0f = s0 - __uint_as_float(bs0 & 0xFFFF0000u);
      float l1f = s1 - __uint_as_float(bs1 & 0xFFFF0000u);
      u32 lw = (__float_as_uint(l0f) >> 16) | (__float_as_uint(l1f) & 0xFFFF0000u);
      int eidx = row * WD + (((o0 >> 3) ^ (row & 7)) * 8) + (o0 & 7);
      *(u32*)&Hhi[eidx] = hw;
      *(u32*)&Hlo[eidx] = lw;
    }
  }
  __syncthreads();

  // ---- 7 hidden layers via MFMA ----
  #pragma unroll 1
  for (int l = 0; l < 7; l++){
    f32x16 acc[3];
    #pragma unroll
    for (int mt = 0; mt < 3; mt++)
      #pragma unroll
      for (int j = 0; j < 16; j++) acc[mt][j] = 0.f;
    KMAIN
    float g  = G[((l + 1) * NB + bidx) * WD + col];
    float e  = Bt[((l + 1) * NB + bidx) * WD + col];
    float bi = bsp[l * WD + col];
    __syncthreads();   // everyone done reading planes
    #pragma unroll
    for (int mt = 0; mt < 3; mt++){
      #pragma unroll
      for (int rg = 0; rg < 16; rg++){
        int row = mt * 32 + (rg & 3) + 8 * (rg >> 2) + 4 * khalf;
        float a = acc[mt][rg] + bi;
        float s = fast_sin(fmaf(g, a, e));
        u32 sb = __float_as_uint(s);
        int eidx = row * WD + ((((col >> 3) ^ (row & 7))) * 8) + (col & 7);
        Hhi[eidx] = (u16)(sb >> 16);
        float sl = s - __uint_as_float(sb & 0xFFFF0000u);
        Hlo[eidx] = (u16)(__float_as_uint(sl) >> 16);
      }
    }
    SETW(l + 1); PREF4;   // next layer's (or view layer's) first 4 B-chunks
    __syncthreads();
  }

  // ---- view layer K-loop (lay 7 of planes, prefetched in last iteration) ----
  f32x16 acc[3];
  #pragma unroll
  for (int mt = 0; mt < 3; mt++)
    #pragma unroll
    for (int j = 0; j < 16; j++) acc[mt][j] = 0.f;
  KMAIN
  // view tail weights (cols 256..258) + bias, per output col
  float vt0 = vw[(size_t)col * 259 + 256];
  float vt1 = vw[(size_t)col * 259 + 257];
  float vt2 = vw[(size_t)col * 259 + 258];
  float vbv = vb[col];
  float gv = G[(8 * NB + bidx) * WD + col];
  float ev = Bt[(8 * NB + bidx) * WD + col];

  // ---- sigma head (reads layer-7 planes, before epilogue overwrites) ----
  if (t < MP){
    float a = 0.f;
    #pragma unroll 4
    for (int c = 0; c < 32; c++){
      int eb = t * WD + ((c ^ (t & 7)) * 8);
      short8v hv = *(const short8v*)(&Hhi[eb]);
      short8v lv = *(const short8v*)(&Hlo[eb]);
      #pragma unroll
      for (int j = 0; j < 8; j++){
        float h = __uint_as_float(((u32)(u16)hv[j]) << 16)
                + __uint_as_float(((u32)(u16)lv[j]) << 16);
        a = fmaf(h, swl[c * 8 + j], a);
      }
    }
    sdfl[t] = a + sgb[0];
  }
  __syncthreads();

  // ---- view epilogue: feat = sin(g*(acc + dir-term) + e) -> planes ----
  #pragma unroll
  for (int mt = 0; mt < 3; mt++){
    #pragma unroll
    for (int rg = 0; rg < 16; rg++){
      int row = mt * 32 + (rg & 3) + 8 * (rg >> 2) + 4 * khalf;
      int ray = (row >= 48) ? ((row >= 72) ? 3 : 2) : ((row >= 24) ? 1 : 0);
      float c = vd[ray][0] * vt0 + vd[ray][1] * vt1 + vd[ray][2] * vt2 + vbv;
      float a = acc[mt][rg] + c;
      float s = fast_sin(fmaf(gv, a, ev));
      u32 sb = __float_as_uint(s);
      int eidx = row * WD + ((((col >> 3) ^ (row & 7))) * 8) + (col & 7);
      Hhi[eidx] = (u16)(sb >> 16);
      float sl = s - __uint_as_float(sb & 0xFFFF0000u);
      Hlo[eidx] = (u16)(__float_as_uint(sl) >> 16);
    }
  }
  __syncthreads();

  // ---- rgb head (reads feat planes) ----
  if (t < MP){
    float a0 = 0.f, a1 = 0.f, a2 = 0.f;
    #pragma unroll 4
    for (int c = 0; c < 32; c++){
      int eb = t * WD + ((c ^ (t & 7)) * 8);
      short8v hv = *(const short8v*)(&Hhi[eb]);
      short8v lv = *(const short8v*)(&Hlo[eb]);
      #pragma unroll
      for (int j = 0; j < 8; j++){
        float h = __uint_as_float(((u32)(u16)hv[j]) << 16)
                + __uint_as_float(((u32)(u16)lv[j]) << 16);
        int k = c * 8 + j;
        a0 = fmaf(h, rwl[0][k], a0);
        a1 = fmaf(h, rwl[1][k], a1);
        a2 = fmaf(h, rwl[2][k], a2);
      }
    }
    rgbl[t][0] = a0 + rgbb[0];
    rgbl[t][1] = a1 + rgbb[1];
    rgbl[t][2] = a2 + rgbb[2];
  }
  __syncthreads();

  // ---- volume integration weights + rgb_map (one thread per ray) ----
  if (t < RPB){
    int r = t;
    int ray = ray0 + r;
    float nr = nearv[bidx], fr = farv[bidx];
    float dnv = dn[r];
    float bet = sbeta[0];
    float vis = 1.f, wsum = 0.f, cr = 0.f, cg = 0.f, cb = 0.f;
    const float C = (1.0f - 1.0f / NS) / (NS - 1);
    #pragma unroll
    for (int s = 0; s < NS; s++){
      float w;
      if (s < NS - 1){
        float t0v = s * C, t1v = (s + 1) * C;
        float z0 = nr * (1.f - t0v) + fr * t0v;
        float z1 = nr * (1.f - t1v) + fr * t1v;
        float dist = (z1 - z0) * dnv;
        float sg = sigm(-sdfl[r * NS + s] / bet) / bet;
        float al = 1.f - expf(-sg * dist);
        w = al * vis;
        vis *= (1.f - al + 1e-10f);
        wsum += w;
      } else {
        w = 1.f - wsum;
      }
      wtl[r][s] = w;
      cr += w * sigm(rgbl[r * NS + s][0]);
      cg += w * sigm(rgbl[r * NS + s][1]);
      cb += w * sigm(rgbl[r * NS + s][2]);
    }
    size_t ob = (size_t)ray * 259;
    out[ob + 0] = -1.f + 2.f * cr;
    out[ob + 1] = -1.f + 2.f * cg;
    out[ob + 2] = -1.f + 2.f * cb;
  }
  __syncthreads();

  // ---- feature map: sum_s w_s * feat_s ----
  {
    float f0 = 0.f, f1 = 0.f;
    #pragma unroll
    for (int s = 0; s < NS; s++){
      int row = mb + s;
      float w = wtl[mg][s];
      int eidx = row * WD + (((o0 >> 3) ^ (row & 7)) * 8) + (o0 & 7);
      u32 wh = *(const u32*)&Hhi[eidx];
      u32 wl = *(const u32*)&Hlo[eidx];
      float fa = __uint_as_float(wh << 16) + __uint_as_float(wl << 16);
      float fb = __uint_as_float(wh & 0xFFFF0000u) + __uint_as_float(wl & 0xFFFF0000u);
      f0 = fmaf(w, fa, f0);
      f1 = fmaf(w, fb, f1);
    }
    size_t ob = (size_t)(ray0 + mg) * 259 + 3;
    out[ob + o0] = f0;
    out[ob + o1] = f1;
  }
}

extern "C" void kernel_launch(void* const* d_in, const int* in_sizes, int n_in,
                              void* d_out, int out_size, void* d_ws, size_t ws_size,
                              hipStream_t stream) {
  (void)in_sizes; (void)n_in; (void)out_size;
  const float* pose   = (const float*)d_in[0];
  const float* focal  = (const float*)d_in[1];
  const float* nearv  = (const float*)d_in[2];
  const float* farv   = (const float*)d_in[3];
  const float* styles = (const float*)d_in[4];
  const float* w0     = (const float*)d_in[5];
  const float* b0     = (const float*)d_in[6];
  const float* wsp    = (const float*)d_in[7];
  const float* bsp    = (const float*)d_in[8];
  const float* gw8    = (const float*)d_in[9];
  const float* gb8    = (const float*)d_in[10];
  const float* bw8    = (const float*)d_in[11];
  const float* bb8    = (const float*)d_in[12];
  const float* vw     = (const float*)d_in[13];
  const float* vb     = (const float*)d_in[14];
  const float* vgw    = (const float*)d_in[15];
  const float* vgb    = (const float*)d_in[16];
  const float* vbw    = (const float*)d_in[17];
  const float* vbb    = (const float*)d_in[18];
  const float* rgbw   = (const float*)d_in[19];
  const float* rgbb   = (const float*)d_in[20];
  const float* sgw    = (const float*)d_in[21];
  const float* sgb    = (const float*)d_in[22];
  const float* sbeta  = (const float*)d_in[23];

  float* G  = (float*)d_ws;
  float* Bt = G + 9 * NB * WD;                       // 4608 floats
  float* out = (float*)d_out;

  const size_t plane_off = 36864;                    // bytes (G+Bt)
  const size_t plane_elems = (size_t)8 * WD * WD;    // 524288 u16 per plane

  u16* Whi = (u16*)((char*)d_ws + plane_off);
  u16* Wlo = Whi + plane_elems;

  film_kernel<<<dim3(18), dim3(256), 0, stream>>>(styles, gw8, gb8, bw8, bb8,
                                                  vgw, vgb, vbw, vbb, G, Bt);
  prep_kernel<<<dim3(512), dim3(256), 0, stream>>>(wsp, vw, Whi, Wlo);
  render_mfma<<<dim3(NBLK), dim3(NTH), 0, stream>>>(pose, focal, nearv, farv,
      w0, b0, bsp, vw, vb, rgbw, rgbb, sgw, sgb, sbeta, G, Bt, Whi, Wlo, out);
}